// Round 6
// baseline (20.225 us; speedup 1.0000x reference)
//
#include <hip/hip_runtime.h>

// out[b][n][m] = ||A[b][n]||^2 + ||B[b][m]||^2 - 2*A[b][n].B[b][m]
// f16 MFMA dot (abs err << 5.32 threshold), fp32 norms.
// R6 = R5 with the nontemporal store done through an ext_vector type
// (clang rejects HIP_vector_type float4* for __builtin_nontemporal_store).

#define B_ 4
#define N_ 1024
#define M_ 1024
#define D_ 64
#define BN 64    // n-rows per block
#define BM 64    // m-cols per block

typedef __attribute__((ext_vector_type(8))) __fp16 f16x8;
typedef __attribute__((ext_vector_type(2))) __fp16 f16x2;
typedef __attribute__((ext_vector_type(4))) float f32x4;

union F16x8 {
  f16x8 v;
  f16x2 h[4];
};

// Load 8 consecutive fp32 (16B-aligned), convert to f16x8 (RTZ).
__device__ __forceinline__ f16x8 load_frag8(const float* __restrict__ p) {
  float4 v0 = *reinterpret_cast<const float4*>(p);
  float4 v1 = *reinterpret_cast<const float4*>(p + 4);
  F16x8 r;
  r.h[0] = __builtin_amdgcn_cvt_pkrtz(v0.x, v0.y);
  r.h[1] = __builtin_amdgcn_cvt_pkrtz(v0.z, v0.w);
  r.h[2] = __builtin_amdgcn_cvt_pkrtz(v1.x, v1.y);
  r.h[3] = __builtin_amdgcn_cvt_pkrtz(v1.z, v1.w);
  return r.v;
}

__global__ __launch_bounds__(256, 4)
void dist2_mfma(const float* __restrict__ A, const float* __restrict__ Bm,
                float* __restrict__ out) {
  __shared__ float naS[BN];
  __shared__ float nbS[BM];

  const int tid = threadIdx.x;
  const int b  = blockIdx.z;
  const int n0 = blockIdx.y * BN;
  const int m0 = blockIdx.x * BM;

  const float* Ab = A  + (size_t)b * N_ * D_;
  const float* Bb = Bm + (size_t)b * M_ * D_;

  // ---- fp32 row norms: threads 0..63 -> A rows, 64..127 -> B rows ----
  if (tid < BN + BM) {
    const float* p = (tid < BN) ? (Ab + (size_t)(n0 + tid) * D_)
                                : (Bb + (size_t)(m0 + tid - BN) * D_);
    float s = 0.f;
    #pragma unroll
    for (int k4 = 0; k4 < D_ / 4; ++k4) {
      float4 v = *reinterpret_cast<const float4*>(p + k4 * 4);
      s = fmaf(v.x, v.x, s);
      s = fmaf(v.y, v.y, s);
      s = fmaf(v.z, v.z, s);
      s = fmaf(v.w, v.w, s);
    }
    if (tid < BN) naS[tid] = s; else nbS[tid - BN] = s;
  }

  // ---- MFMA: 4 waves stacked on n; wave tile 16(n) x 64(m) ----
  const int wid  = tid >> 6;
  const int lane = tid & 63;
  const int lr = lane & 15;      // operand row within 16-group
  const int kb = (lane >> 4) * 8;

  const float* An = Ab + (size_t)(n0 + wid * 16 + lr) * D_;
  const float* Bn = Bb + (size_t)(m0 + lr) * D_;

  f32x4 acc[4];
  #pragma unroll
  for (int j = 0; j < 4; ++j) acc[j] = (f32x4){0.f, 0.f, 0.f, 0.f};

  #pragma unroll
  for (int ks = 0; ks < 2; ++ks) {
    const int k = ks * 32 + kb;
    f16x8 af = load_frag8(An + k);
    f16x8 bf[4];
    #pragma unroll
    for (int mf = 0; mf < 4; ++mf) bf[mf] = load_frag8(Bn + (size_t)mf * 16 * D_ + k);
    // SWAPPED operands: first-operand row (B, m) -> reg dimension
    // -> each lane holds 4 consecutive m -> float4 stores.
    #pragma unroll
    for (int mf = 0; mf < 4; ++mf)
      acc[mf] = __builtin_amdgcn_mfma_f32_16x16x32_f16(bf[mf], af, acc[mf], 0, 0, 0);
  }

  __syncthreads();   // norms ready

  // ---- epilogue: n = wid*16 + (lane&15), m = mf*16 + (lane>>4)*4 + reg ----
  const int mg = (lane >> 4) * 4;
  const int nloc = wid * 16 + (lane & 15);
  const float na = naS[nloc];
  float* orow = out + ((size_t)b * N_ + n0 + nloc) * M_ + m0;

  #pragma unroll
  for (int mf = 0; mf < 4; ++mf) {
    const int mloc = mf * 16 + mg;
    f32x4 nb = *reinterpret_cast<const f32x4*>(&nbS[mloc]);
    f32x4 a = acc[mf];
    f32x4 r;
    r[0] = fmaf(-2.f, a[0], na + nb[0]);
    r[1] = fmaf(-2.f, a[1], na + nb[1]);
    r[2] = fmaf(-2.f, a[2], na + nb[2]);
    r[3] = fmaf(-2.f, a[3], na + nb[3]);
    __builtin_nontemporal_store(r, reinterpret_cast<f32x4*>(orow + mloc));
  }
}

extern "C" void kernel_launch(void* const* d_in, const int* in_sizes, int n_in,
                              void* d_out, int out_size, void* d_ws, size_t ws_size,
                              hipStream_t stream) {
  const float* A  = (const float*)d_in[0];
  const float* Bm = (const float*)d_in[1];
  float* out = (float*)d_out;
  dim3 grid(M_ / BM, N_ / BN, B_);
  dist2_mfma<<<grid, dim3(256), 0, stream>>>(A, Bm, out);
}

// Round 7
// 17.430 us; speedup vs baseline: 1.1604x; 1.1604x over previous
//
#include <hip/hip_runtime.h>

// out[b][n][m] = ||A[b][n]||^2 + ||B[b][m]||^2 - 2*A[b][n].B[b][m]
// f16 MFMA dot (abs err << 5.32 threshold), fp32 norms.
// R7 = revert to best-measured structure (R3, 16.9us): 128x128 tile,
// 512 thr, direct-from-global fragments. Session conclusion: dispatch
// floor ~15us dominates; kernel-side work ~3us (write-bound).

#define B_ 4
#define N_ 1024
#define M_ 1024
#define D_ 64
#define BN 128
#define BM 128

typedef __attribute__((ext_vector_type(8))) __fp16 f16x8;
typedef __attribute__((ext_vector_type(2))) __fp16 f16x2;
typedef __attribute__((ext_vector_type(4))) float f32x4;

union F16x8 {
  f16x8 v;
  f16x2 h[4];
};

// Load 8 consecutive fp32 (16B-aligned), convert to f16x8 (RTZ).
__device__ __forceinline__ f16x8 load_frag8(const float* __restrict__ p) {
  float4 v0 = *reinterpret_cast<const float4*>(p);
  float4 v1 = *reinterpret_cast<const float4*>(p + 4);
  F16x8 r;
  r.h[0] = __builtin_amdgcn_cvt_pkrtz(v0.x, v0.y);
  r.h[1] = __builtin_amdgcn_cvt_pkrtz(v0.z, v0.w);
  r.h[2] = __builtin_amdgcn_cvt_pkrtz(v1.x, v1.y);
  r.h[3] = __builtin_amdgcn_cvt_pkrtz(v1.z, v1.w);
  return r.v;
}

__global__ __launch_bounds__(512, 4)
void dist2_mfma(const float* __restrict__ A, const float* __restrict__ Bm,
                float* __restrict__ out) {
  __shared__ float naS[BN];
  __shared__ float nbS[BM];

  const int tid = threadIdx.x;
  const int b  = blockIdx.z;
  const int n0 = blockIdx.y * BN;
  const int m0 = blockIdx.x * BM;

  const float* Ab = A  + (size_t)b * N_ * D_;
  const float* Bb = Bm + (size_t)b * M_ * D_;

  // ---- fp32 row norms (threads 0..255; one row each) ----
  if (tid < BN + BM) {
    const float* p = (tid < BN) ? (Ab + (size_t)(n0 + tid) * D_)
                                : (Bb + (size_t)(m0 + tid - BN) * D_);
    float s = 0.f;
    #pragma unroll
    for (int k4 = 0; k4 < D_ / 4; ++k4) {
      float4 v = *reinterpret_cast<const float4*>(p + k4 * 4);
      s = fmaf(v.x, v.x, s);
      s = fmaf(v.y, v.y, s);
      s = fmaf(v.z, v.z, s);
      s = fmaf(v.w, v.w, s);
    }
    if (tid < BN) naS[tid] = s; else nbS[tid - BN] = s;
  }

  // ---- MFMA: 8 waves as 2(n) x 4(m); wave tile 64(n) x 32(m) ----
  const int wid  = tid >> 6;
  const int lane = tid & 63;
  const int wn = wid >> 2;       // n offset wn*64
  const int wm = wid & 3;        // m offset wm*32
  const int lr = lane & 15;
  const int kb = (lane >> 4) * 8;

  const float* An = Ab + (size_t)(n0 + wn * 64 + lr) * D_;
  const float* Bn = Bb + (size_t)(m0 + wm * 32 + lr) * D_;

  f32x4 acc[4][2];
  #pragma unroll
  for (int i = 0; i < 4; ++i)
    #pragma unroll
    for (int j = 0; j < 2; ++j) acc[i][j] = (f32x4){0.f, 0.f, 0.f, 0.f};

  #pragma unroll
  for (int ks = 0; ks < 2; ++ks) {
    const int k = ks * 32 + kb;
    f16x8 af[4], bf[2];
    #pragma unroll
    for (int nf = 0; nf < 4; ++nf) af[nf] = load_frag8(An + (size_t)nf * 16 * D_ + k);
    #pragma unroll
    for (int mf = 0; mf < 2; ++mf) bf[mf] = load_frag8(Bn + (size_t)mf * 16 * D_ + k);
    // SWAPPED operands: first-operand row (B, m) -> reg dim -> float4 stores.
    #pragma unroll
    for (int nf = 0; nf < 4; ++nf)
      #pragma unroll
      for (int mf = 0; mf < 2; ++mf)
        acc[nf][mf] = __builtin_amdgcn_mfma_f32_16x16x32_f16(bf[mf], af[nf], acc[nf][mf], 0, 0, 0);
  }

  __syncthreads();   // norms ready

  // ---- epilogue: n = wn*64+nf*16+(lane&15), m = wm*32+mf*16+(lane>>4)*4+reg ----
  const int mg = (lane >> 4) * 4;

  #pragma unroll
  for (int nf = 0; nf < 4; ++nf) {
    const int nloc = wn * 64 + nf * 16 + (lane & 15);
    const float na = naS[nloc];
    float* orow = out + ((size_t)b * N_ + n0 + nloc) * M_ + m0;
    #pragma unroll
    for (int mf = 0; mf < 2; ++mf) {
      const int mloc = wm * 32 + mf * 16 + mg;
      f32x4 nb = *reinterpret_cast<const f32x4*>(&nbS[mloc]);
      f32x4 a = acc[nf][mf];
      f32x4 r;
      r[0] = fmaf(-2.f, a[0], na + nb[0]);
      r[1] = fmaf(-2.f, a[1], na + nb[1]);
      r[2] = fmaf(-2.f, a[2], na + nb[2]);
      r[3] = fmaf(-2.f, a[3], na + nb[3]);
      *reinterpret_cast<f32x4*>(orow + mloc) = r;
    }
  }
}

extern "C" void kernel_launch(void* const* d_in, const int* in_sizes, int n_in,
                              void* d_out, int out_size, void* d_ws, size_t ws_size,
                              hipStream_t stream) {
  const float* A  = (const float*)d_in[0];
  const float* Bm = (const float*)d_in[1];
  float* out = (float*)d_out;
  dim3 grid(M_ / BM, N_ / BN, B_);
  dist2_mfma<<<grid, dim3(512), 0, stream>>>(A, Bm, out);
}